// Round 3
// baseline (415.322 us; speedup 1.0000x reference)
//
#include <hip/hip_runtime.h>
#include <cstddef>

#define NC 64

__global__ __launch_bounds__(64, 1)   // min 1 wave/EU: unlock full VGPR budget so E[64] stays resident
void crf_nll_kernel(const float* __restrict__ logits,
                    const float* __restrict__ trans,
                    const float* __restrict__ init_alphas,
                    const int*  __restrict__ lengths,
                    const int*  __restrict__ tags,
                    float* __restrict__ out,
                    int N, int T)
{
    const int n = blockIdx.x;
    const int lane = threadIdx.x;          // 0..63, owns class row `lane`
    const float* lg = logits + (size_t)n * T * NC;
    const int len = lengths[n];            // in [2, T]
    const int Tm1 = T - 1;

    __shared__ __align__(16) float v_lds[NC];

    // E row for this lane: exp(trans[lane][j]) -> 64 VGPRs (must stay resident!)
    float E[NC];
    #pragma unroll
    for (int j = 0; j < NC; ++j)
        E[j] = __expf(trans[lane * NC + j]);

    // alpha_0 = init + logits[0]; linear domain v = exp(alpha - L)
    float a0 = init_alphas[lane] + lg[lane];
    float L  = __int_as_float(__builtin_amdgcn_readfirstlane(__float_as_int(a0)));
    float v  = __expf(a0 - L);

    // software pipeline, depth 6: f = exp(row t); r1..r5 = raw rows t+1..t+5
    float f  = __expf(lg[NC * 1 + lane]);                      // row 1 (len>=2)
    float r1 = lg[NC * (2 < Tm1 ? 2 : Tm1) + lane];
    float r2 = lg[NC * (3 < Tm1 ? 3 : Tm1) + lane];
    float r3 = lg[NC * (4 < Tm1 ? 4 : Tm1) + lane];
    float r4 = lg[NC * (5 < Tm1 ? 5 : Tm1) + lane];
    float r5 = lg[NC * (6 < Tm1 ? 6 : Tm1) + lane];

    for (int t = 1; t < len; ++t) {
        v_lds[lane] = v;                   // single wave: LDS pipe is in-order, no barrier

        int prow = t + 6; prow = prow < Tm1 ? prow : Tm1;      // clamp, off-chain
        float rnew = lg[NC * prow + lane]; // prefetch, ~5 steps of slack
        float fn = __expf(r1);             // exp for NEXT step, off current chain

        const float4* p4 = reinterpret_cast<const float4*>(v_lds);
        float s0 = 0.f, s1 = 0.f, s2 = 0.f, s3 = 0.f;
        #pragma unroll
        for (int jj = 0; jj < 16; ++jj) {
            const float4 pv = p4[jj];      // broadcast reads, conflict-free
            s0 = __fmaf_rn(E[4*jj+0], pv.x, s0);
            s1 = __fmaf_rn(E[4*jj+1], pv.y, s1);
            s2 = __fmaf_rn(E[4*jj+2], pv.z, s2);
            s3 = __fmaf_rn(E[4*jj+3], pv.w, s3);
        }
        const float dot = (s0 + s1) + (s2 + s3);
        v = f * dot;                       // linear-domain update

        if ((t & 7) == 0) {
            // exact power-of-2 rescale: strip lane-0's exponent
            unsigned bits = (unsigned)__builtin_amdgcn_readfirstlane((int)__float_as_uint(v));
            int e = (int)((bits >> 23) & 0xFF);                // biased exponent
            v *= __uint_as_float((unsigned)(254 - e) << 23);   // *= 2^(127-e)
            L += (float)(e - 127) * 0.6931471805599453f;
        }
        f = fn; r1 = r2; r2 = r3; r3 = r4; r4 = r5; r5 = rnew;
    }

    // logZ = L + log(sum_i v_i)
    float p2 = v;
    #pragma unroll
    for (int off = 32; off; off >>= 1) p2 += __shfl_xor(p2, off);
    const float logZ = L + __logf(p2);

    // gold score: first + sum_{t>=1} trans[tag_t, tag_{t-1}] + logit[t, tag_t]
    const int* tg = tags + (size_t)n * T;
    float g = 0.f;
    for (int t = 1 + lane; t < len; t += 64) {
        const int cur = tg[t];
        const int prv = tg[t - 1];
        g += trans[cur * NC + prv] + lg[t * NC + cur];
    }
    #pragma unroll
    for (int off = 32; off; off >>= 1) g += __shfl_xor(g, off);

    if (lane == 0) {
        const int t0 = tg[0];
        const float gold = init_alphas[t0] + lg[t0] + g;
        out[n] = logZ - gold;
    }
}

extern "C" void kernel_launch(void* const* d_in, const int* in_sizes, int n_in,
                              void* d_out, int out_size, void* d_ws, size_t ws_size,
                              hipStream_t stream)
{
    const float* logits = (const float*)d_in[0];   // [N][T][C] f32
    const float* trans  = (const float*)d_in[1];   // [C][C]    f32
    const float* inita  = (const float*)d_in[2];   // [C]       f32
    const int*   lens   = (const int*)d_in[3];     // [N]       i32
    const int*   tags   = (const int*)d_in[4];     // [N][T]    i32
    float*       out    = (float*)d_out;           // [N]       f32

    const int N = 512, T = 1024;
    crf_nll_kernel<<<N, 64, 0, stream>>>(logits, trans, inita, lens, tags, out, N, T);
}

// Round 4
// 403.174 us; speedup vs baseline: 1.0301x; 1.0301x over previous
//
#include <hip/hip_runtime.h>
#include <cstddef>

#define NC 64

// X-macro over the 64 transition-row entries: X(token, index)
#define E_LIST(X) \
 X(00,0)  X(01,1)  X(02,2)  X(03,3)  X(04,4)  X(05,5)  X(06,6)  X(07,7) \
 X(08,8)  X(09,9)  X(10,10) X(11,11) X(12,12) X(13,13) X(14,14) X(15,15) \
 X(16,16) X(17,17) X(18,18) X(19,19) X(20,20) X(21,21) X(22,22) X(23,23) \
 X(24,24) X(25,25) X(26,26) X(27,27) X(28,28) X(29,29) X(30,30) X(31,31) \
 X(32,32) X(33,33) X(34,34) X(35,35) X(36,36) X(37,37) X(38,38) X(39,39) \
 X(40,40) X(41,41) X(42,42) X(43,43) X(44,44) X(45,45) X(46,46) X(47,47) \
 X(48,48) X(49,49) X(50,50) X(51,51) X(52,52) X(53,53) X(54,54) X(55,55) \
 X(56,56) X(57,57) X(58,58) X(59,59) X(60,60) X(61,61) X(62,62) X(63,63)

#define E_DECL(tok, idx) float E##tok;
#define E_LOAD(tok, idx) E##tok = __expf(tr[idx]);
#define E_PIN(tok, idx)  asm volatile("" : "+v"(E##tok));

// one float4 chunk of the dot product; accumulators chosen by caller
#define DOT(jj, A, B, C, D, sa, sb, sc, sd)            \
    {                                                  \
        const float4 pv = p4[jj];                      \
        sa = __fmaf_rn(E##A, pv.x, sa);                \
        sb = __fmaf_rn(E##B, pv.y, sb);                \
        sc = __fmaf_rn(E##C, pv.z, sc);                \
        sd = __fmaf_rn(E##D, pv.w, sd);                \
    }

__global__ __launch_bounds__(64, 1)
void crf_nll_kernel(const float* __restrict__ logits,
                    const float* __restrict__ trans,
                    const float* __restrict__ init_alphas,
                    const int*  __restrict__ lengths,
                    const int*  __restrict__ tags,
                    float* __restrict__ out,
                    int N, int T)
{
    const int n = blockIdx.x;
    const int lane = threadIdx.x;          // 0..63, owns class row `lane`
    const float* lg = logits + (size_t)n * T * NC;
    const int len = lengths[n];            // in [2, T]
    const int Tm1 = T - 1;

    __shared__ __align__(16) float v_lds[NC];

    // exp(trans[lane][j]) as 64 NAMED scalars, pinned into VGPRs so the
    // compiler cannot spill-to-scratch or rematerialize the loads.
    const float* tr = trans + lane * NC;
    E_LIST(E_DECL)
    E_LIST(E_LOAD)
    E_LIST(E_PIN)

    // alpha_0 = init + logits[0]; linear domain v = exp(alpha - L)
    float a0 = init_alphas[lane] + lg[lane];
    float L  = __int_as_float(__builtin_amdgcn_readfirstlane(__float_as_int(a0)));
    float v  = __expf(a0 - L);

    // software pipeline, depth 6: f = exp(row t); r1..r5 = raw rows t+1..t+5
    float f  = __expf(lg[NC * 1 + lane]);                      // row 1 (len>=2)
    float r1 = lg[NC * (2 < Tm1 ? 2 : Tm1) + lane];
    float r2 = lg[NC * (3 < Tm1 ? 3 : Tm1) + lane];
    float r3 = lg[NC * (4 < Tm1 ? 4 : Tm1) + lane];
    float r4 = lg[NC * (5 < Tm1 ? 5 : Tm1) + lane];
    float r5 = lg[NC * (6 < Tm1 ? 6 : Tm1) + lane];

    for (int t = 1; t < len; ++t) {
        v_lds[lane] = v;                   // single wave: DS pipe in-order, no barrier

        int prow = t + 6; prow = prow < Tm1 ? prow : Tm1;      // clamp, off-chain
        float rnew = lg[NC * prow + lane]; // prefetch, ~5 steps of slack
        float fn = __expf(r1);             // exp for NEXT step, off current chain

        const float4* p4 = reinterpret_cast<const float4*>(v_lds);
        float s0 = 0.f, s1 = 0.f, s2 = 0.f, s3 = 0.f;
        float s4 = 0.f, s5 = 0.f, s6 = 0.f, s7 = 0.f;
        DOT( 0, 00,01,02,03, s0,s1,s2,s3)
        DOT( 1, 04,05,06,07, s4,s5,s6,s7)
        DOT( 2, 08,09,10,11, s0,s1,s2,s3)
        DOT( 3, 12,13,14,15, s4,s5,s6,s7)
        DOT( 4, 16,17,18,19, s0,s1,s2,s3)
        DOT( 5, 20,21,22,23, s4,s5,s6,s7)
        DOT( 6, 24,25,26,27, s0,s1,s2,s3)
        DOT( 7, 28,29,30,31, s4,s5,s6,s7)
        DOT( 8, 32,33,34,35, s0,s1,s2,s3)
        DOT( 9, 36,37,38,39, s4,s5,s6,s7)
        DOT(10, 40,41,42,43, s0,s1,s2,s3)
        DOT(11, 44,45,46,47, s4,s5,s6,s7)
        DOT(12, 48,49,50,51, s0,s1,s2,s3)
        DOT(13, 52,53,54,55, s4,s5,s6,s7)
        DOT(14, 56,57,58,59, s0,s1,s2,s3)
        DOT(15, 60,61,62,63, s4,s5,s6,s7)
        const float dot = ((s0 + s4) + (s1 + s5)) + ((s2 + s6) + (s3 + s7));
        v = f * dot;                       // linear-domain update

        if ((t & 7) == 0) {
            // exact power-of-2 rescale: strip lane-0's exponent
            unsigned bits = (unsigned)__builtin_amdgcn_readfirstlane((int)__float_as_uint(v));
            int e = (int)((bits >> 23) & 0xFF);                // biased exponent
            v *= __uint_as_float((unsigned)(254 - e) << 23);   // *= 2^(127-e)
            L += (float)(e - 127) * 0.6931471805599453f;
        }
        f = fn; r1 = r2; r2 = r3; r3 = r4; r4 = r5; r5 = rnew;
    }

    // logZ = L + log(sum_i v_i)
    float p2 = v;
    #pragma unroll
    for (int off = 32; off; off >>= 1) p2 += __shfl_xor(p2, off);
    const float logZ = L + __logf(p2);

    // gold score: first + sum_{t>=1} trans[tag_t, tag_{t-1}] + logit[t, tag_t]
    const int* tg = tags + (size_t)n * T;
    float g = 0.f;
    for (int t = 1 + lane; t < len; t += 64) {
        const int cur = tg[t];
        const int prv = tg[t - 1];
        g += trans[cur * NC + prv] + lg[t * NC + cur];
    }
    #pragma unroll
    for (int off = 32; off; off >>= 1) g += __shfl_xor(g, off);

    if (lane == 0) {
        const int t0 = tg[0];
        const float gold = init_alphas[t0] + lg[t0] + g;
        out[n] = logZ - gold;
    }
}

extern "C" void kernel_launch(void* const* d_in, const int* in_sizes, int n_in,
                              void* d_out, int out_size, void* d_ws, size_t ws_size,
                              hipStream_t stream)
{
    const float* logits = (const float*)d_in[0];   // [N][T][C] f32
    const float* trans  = (const float*)d_in[1];   // [C][C]    f32
    const float* inita  = (const float*)d_in[2];   // [C]       f32
    const int*   lens   = (const int*)d_in[3];     // [N]       i32
    const int*   tags   = (const int*)d_in[4];     // [N][T]    i32
    float*       out    = (float*)d_out;           // [N]       f32

    const int N = 512, T = 1024;
    crf_nll_kernel<<<N, 64, 0, stream>>>(logits, trans, inita, lens, tags, out, N, T);
}

// Round 5
// 308.019 us; speedup vs baseline: 1.3484x; 1.3089x over previous
//
#include <hip/hip_runtime.h>
#include <cstdint>
#include <cstddef>

#define NC 64
#define EROW 36   // dwords per packed-E row (32 data + 4 pad; 9 chunks, odd -> balanced banks)

typedef _Float16 half2_t __attribute__((ext_vector_type(2)));

static __device__ __forceinline__ float dot2acc(uint32_t a, uint32_t b, float c) {
#if __has_builtin(__builtin_amdgcn_fdot2)
    return __builtin_amdgcn_fdot2(__builtin_bit_cast(half2_t, a),
                                  __builtin_bit_cast(half2_t, b), c, false);
#else
    half2_t ha = __builtin_bit_cast(half2_t, a), hb = __builtin_bit_cast(half2_t, b);
    return c + (float)ha[0] * (float)hb[0] + (float)ha[1] * (float)hb[1];
#endif
}

template <int CTRL>
static __device__ __forceinline__ float dppf(float x) {
    return __int_as_float(__builtin_amdgcn_update_dpp(
        0, __float_as_int(x), CTRL, 0xf, 0xf, true));
}
// classic GCN wave64 reduce: row_shr 1,2,4,8 then bcast15, bcast31; lane 63 has result
static __device__ __forceinline__ float wave_max_bcast(float x) {
    x = fmaxf(x, dppf<0x111>(x));
    x = fmaxf(x, dppf<0x112>(x));
    x = fmaxf(x, dppf<0x114>(x));
    x = fmaxf(x, dppf<0x118>(x));
    x = fmaxf(x, dppf<0x142>(x));
    x = fmaxf(x, dppf<0x143>(x));
    return __int_as_float(__builtin_amdgcn_readlane(__float_as_int(x), 63));
}
static __device__ __forceinline__ float wave_sum_bcast(float x) {
    x = x + dppf<0x111>(x);
    x = x + dppf<0x112>(x);
    x = x + dppf<0x114>(x);
    x = x + dppf<0x118>(x);
    x = x + dppf<0x142>(x);
    x = x + dppf<0x143>(x);
    return __int_as_float(__builtin_amdgcn_readlane(__float_as_int(x), 63));
}

__global__ __launch_bounds__(64, 1)
void crf_nll_kernel(const float* __restrict__ logits,
                    const float* __restrict__ trans,
                    const float* __restrict__ init_alphas,
                    const int*  __restrict__ lengths,
                    const int*  __restrict__ tags,
                    float* __restrict__ out,
                    int N, int T)
{
    const int n = blockIdx.x;
    const int lane = threadIdx.x;              // 0..63, owns class row `lane`
    const float* lg = logits + (size_t)n * T * NC;
    const int len = lengths[n];                // in [2, T]
    const int Tm1 = T - 1;

    __shared__ __align__(16) uint32_t E_pk[64 * EROW];  // exp(trans) packed f16x2
    __shared__ __align__(16) uint16_t v_pk[NC + 8];     // state, packed f16

    // ---- fill packed E: word (row,k) = {f16(exp(tr[row][2k])), f16(exp(tr[row][2k+1]))}
    const float2* tr2 = reinterpret_cast<const float2*>(trans);
    #pragma unroll
    for (int i = lane; i < 64 * 32; i += 64) {
        int row = i >> 5, k = i & 31;
        float2 t2 = tr2[i];                    // classes 2k, 2k+1 of row
        uint32_t lo = __builtin_bit_cast(uint16_t, (_Float16)__expf(t2.x));
        uint32_t hi = __builtin_bit_cast(uint16_t, (_Float16)__expf(t2.y));
        E_pk[row * EROW + k] = (hi << 16) | lo;
    }

    // ---- init state: alpha0 = init + logits[0]; L = max; v = exp(alpha0 - L) packed
    float a0 = init_alphas[lane] + lg[lane];
    float L  = wave_max_bcast(a0);
    float vn = __expf(a0 - L);                 // in (0, 1]
    v_pk[lane] = __builtin_bit_cast(uint16_t, (_Float16)vn);
    // single wave: DS pipe is in-order; writes above are visible to reads below

    // ---- depth-8 register prefetch of raw logit rows t+0.. (row for step t is rb[0])
    float rb[8];
    #pragma unroll
    for (int k = 0; k < 8; ++k) {
        int r = 1 + k; r = r < Tm1 ? r : Tm1;
        rb[k] = lg[r * NC + lane];
    }

    const uint4* Erow = reinterpret_cast<const uint4*>(&E_pk[lane * EROW]);
    const uint4* vb4  = reinterpret_cast<const uint4*>(v_pk);

    for (int t = 1; t < len; ++t) {
        float raw = rb[0];
        #pragma unroll
        for (int k = 0; k < 7; ++k) rb[k] = rb[k + 1];
        int prow = t + 8; prow = prow < Tm1 ? prow : Tm1;
        rb[7] = lg[prow * NC + lane];          // issued early, consumed 8 iters later

        float f = __expf(raw);                 // overlaps with LDS reads below

        float c0 = 0.f, c1 = 0.f, c2 = 0.f, c3 = 0.f;
        float c4 = 0.f, c5 = 0.f, c6 = 0.f, c7 = 0.f;
        #pragma unroll
        for (int c = 0; c < 8; ++c) {
            uint4 e4 = Erow[c];                // balanced 8-phase b128
            uint4 w4 = vb4[c];                 // broadcast read
            c0 = dot2acc(e4.x, w4.x, c0);
            c1 = dot2acc(e4.y, w4.y, c1);
            c2 = dot2acc(e4.z, w4.z, c2);
            c3 = dot2acc(e4.w, w4.w, c3);
            // rotate accumulator banks for ILP
            float tmp = c0; c0 = c4; c4 = tmp;
            tmp = c1; c1 = c5; c5 = tmp;
            tmp = c2; c2 = c6; c6 = tmp;
            tmp = c3; c3 = c7; c7 = tmp;
        }
        const float dot = ((c0 + c4) + (c1 + c5)) + ((c2 + c6) + (c3 + c7));
        float v = f * dot;                     // new un-normalized state (positive)

        // exact per-step normalization: strip exponent of wave max
        float m = wave_max_bcast(v);
        unsigned mb = __float_as_uint(m);
        int e = (int)((mb >> 23) & 0xFF);      // biased exponent of max
        float scale = __uint_as_float((unsigned)(254 - e) << 23);  // 2^(127-e)
        vn = v * scale;                        // max in [1,2); rest <= that (f16-safe)
        L += (float)(e - 127) * 0.6931471805599453f;

        v_pk[lane] = __builtin_bit_cast(uint16_t, (_Float16)vn);
    }

    // ---- logZ = L + log(sum_i vn_i)
    const float logZ = L + __logf(wave_sum_bcast(vn));

    // ---- gold score (parallel, off critical path)
    const int* tg = tags + (size_t)n * T;
    float g = 0.f;
    for (int t = 1 + lane; t < len; t += 64) {
        const int cur = tg[t];
        const int prv = tg[t - 1];
        g += trans[cur * NC + prv] + lg[t * NC + cur];
    }
    g = wave_sum_bcast(g);

    if (lane == 0) {
        const int t0 = tg[0];
        const float gold = init_alphas[t0] + lg[t0] + g;
        out[n] = logZ - gold;
    }
}

extern "C" void kernel_launch(void* const* d_in, const int* in_sizes, int n_in,
                              void* d_out, int out_size, void* d_ws, size_t ws_size,
                              hipStream_t stream)
{
    const float* logits = (const float*)d_in[0];   // [N][T][C] f32
    const float* trans  = (const float*)d_in[1];   // [C][C]    f32
    const float* inita  = (const float*)d_in[2];   // [C]       f32
    const int*   lens   = (const int*)d_in[3];     // [N]       i32
    const int*   tags   = (const int*)d_in[4];     // [N][T]    i32
    float*       out    = (float*)d_out;           // [N]       f32

    const int N = 512, T = 1024;
    crf_nll_kernel<<<N, 64, 0, stream>>>(logits, trans, inita, lens, tags, out, N, T);
}

// Round 6
// 210.528 us; speedup vs baseline: 1.9728x; 1.4631x over previous
//
#include <hip/hip_runtime.h>
#include <cstdint>
#include <cstddef>

#define NC 64
#define EROW 36   // dwords per packed-E row (32 data + 4 pad; odd chunk stride -> 2-way max banking, free)
#define LN2 0.6931471805599453f

typedef _Float16 half2_t __attribute__((ext_vector_type(2)));

static __device__ __forceinline__ float dot2acc(uint32_t a, uint32_t b, float c) {
#if __has_builtin(__builtin_amdgcn_fdot2)
    return __builtin_amdgcn_fdot2(__builtin_bit_cast(half2_t, a),
                                  __builtin_bit_cast(half2_t, b), c, false);
#else
    half2_t ha = __builtin_bit_cast(half2_t, a), hb = __builtin_bit_cast(half2_t, b);
    return c + (float)ha[0] * (float)hb[0] + (float)ha[1] * (float)hb[1];
#endif
}

template <int CTRL>
static __device__ __forceinline__ float dppf(float x) {
    return __int_as_float(__builtin_amdgcn_update_dpp(
        0, __float_as_int(x), CTRL, 0xf, 0xf, true));
}
static __device__ __forceinline__ float wave_sum_bcast(float x) {
    x = x + dppf<0x111>(x);
    x = x + dppf<0x112>(x);
    x = x + dppf<0x114>(x);
    x = x + dppf<0x118>(x);
    x = x + dppf<0x142>(x);   // row_bcast15
    x = x + dppf<0x143>(x);   // row_bcast31
    return __int_as_float(__builtin_amdgcn_readlane(__float_as_int(x), 63));
}

__global__ __launch_bounds__(64, 1)
void crf_nll_kernel(const float* __restrict__ logits,
                    const float* __restrict__ trans,
                    const float* __restrict__ init_alphas,
                    const int*  __restrict__ lengths,
                    const int*  __restrict__ tags,
                    float* __restrict__ out,
                    int N, int T)
{
    const int n = blockIdx.x;
    const int lane = threadIdx.x;              // 0..63, owns class row `lane`
    const float* lg = logits + (size_t)n * T * NC;
    const int len = lengths[n];                // in [2, T]
    const int Tm1 = T - 1;

    __shared__ __align__(16) uint32_t E_pk[64 * EROW];  // exp(trans) packed f16x2
    __shared__ __align__(16) uint16_t v_pk[NC + 8];     // state, packed f16

    // ---- fill packed E: word (row,k) = {f16(exp(tr[row][2k])), f16(exp(tr[row][2k+1]))}
    const float2* tr2 = reinterpret_cast<const float2*>(trans);
    #pragma unroll
    for (int i = lane; i < 64 * 32; i += 64) {
        int row = i >> 5, k = i & 31;
        float2 t2 = tr2[i];
        uint32_t lo = (uint32_t)__builtin_bit_cast(uint16_t, (_Float16)__expf(t2.x));
        uint32_t hi = (uint32_t)__builtin_bit_cast(uint16_t, (_Float16)__expf(t2.y));
        E_pk[row * EROW + k] = (hi << 16) | lo;
    }

    // ---- init: alpha0 = init + logits[0]; normalize so lane-0 value = 2^-4
    float a0 = init_alphas[lane] + lg[lane];
    float L  = __int_as_float(__builtin_amdgcn_readfirstlane(__float_as_int(a0)))
               + 4.f * LN2;                    // lane0: exp(a0 - L) = 1/16
    float vn = __expf(a0 - L);
    v_pk[lane] = __builtin_bit_cast(uint16_t, (_Float16)vn);
    // single wave: DS pipe is in-order; no barrier needed anywhere

    const uint4* Erow = reinterpret_cast<const uint4*>(&E_pk[lane * EROW]);
    const uint4* vb4  = reinterpret_cast<const uint4*>(v_pk);

    // one alpha-recursion step given the raw logit value for this row
    auto step = [&](float raw) {
        float f = __expf(raw);                 // off-chain (raw ready long ago)
        float c0 = 0.f, c1 = 0.f, c2 = 0.f, c3 = 0.f;
        float c4 = 0.f, c5 = 0.f, c6 = 0.f, c7 = 0.f;
        #pragma unroll
        for (int c = 0; c < 8; c += 2) {
            uint4 ea = Erow[c], wa = vb4[c];
            c0 = dot2acc(ea.x, wa.x, c0);
            c1 = dot2acc(ea.y, wa.y, c1);
            c2 = dot2acc(ea.z, wa.z, c2);
            c3 = dot2acc(ea.w, wa.w, c3);
            uint4 eb = Erow[c + 1], wb = vb4[c + 1];
            c4 = dot2acc(eb.x, wb.x, c4);
            c5 = dot2acc(eb.y, wb.y, c5);
            c6 = dot2acc(eb.z, wb.z, c6);
            c7 = dot2acc(eb.w, wb.w, c7);
        }
        const float dot = ((c0 + c4) + (c1 + c5)) + ((c2 + c6) + (c3 + c7));
        float v = f * dot;                     // un-normalized new state (positive)

        // normalize: lane-0 value -> [2^-4, 2^-3); exact power-of-2, SALU-cheap
        unsigned bits = (unsigned)__builtin_amdgcn_readfirstlane((int)__float_as_uint(v));
        int e = (int)((bits >> 23) & 0xFF);    // biased exponent of lane-0 value
        float scale = __uint_as_float((unsigned)(250 - e) << 23);   // 2^(123-e)
        vn = v * scale;
        L += (float)(e - 123) * LN2;
        v_pk[lane] = __builtin_bit_cast(uint16_t, (_Float16)vn);
    };

    // ---- depth-8 prefetch in NAMED registers (no rotation -> counted vmcnt waits)
    float r0 = lg[NC * (1 < Tm1 ? 1 : Tm1) + lane];
    float r1 = lg[NC * (2 < Tm1 ? 2 : Tm1) + lane];
    float r2 = lg[NC * (3 < Tm1 ? 3 : Tm1) + lane];
    float r3 = lg[NC * (4 < Tm1 ? 4 : Tm1) + lane];
    float r4 = lg[NC * (5 < Tm1 ? 5 : Tm1) + lane];
    float r5 = lg[NC * (6 < Tm1 ? 6 : Tm1) + lane];
    float r6 = lg[NC * (7 < Tm1 ? 7 : Tm1) + lane];
    float r7 = lg[NC * (8 < Tm1 ? 8 : Tm1) + lane];

    int t = 1;
    for (; t + 8 <= len; t += 8) {             // steps t..t+7 all valid
        int p;
        step(r0); p = t +  8; p = p < Tm1 ? p : Tm1; r0 = lg[NC * p + lane];
        step(r1); p = t +  9; p = p < Tm1 ? p : Tm1; r1 = lg[NC * p + lane];
        step(r2); p = t + 10; p = p < Tm1 ? p : Tm1; r2 = lg[NC * p + lane];
        step(r3); p = t + 11; p = p < Tm1 ? p : Tm1; r3 = lg[NC * p + lane];
        step(r4); p = t + 12; p = p < Tm1 ? p : Tm1; r4 = lg[NC * p + lane];
        step(r5); p = t + 13; p = p < Tm1 ? p : Tm1; r5 = lg[NC * p + lane];
        step(r6); p = t + 14; p = p < Tm1 ? p : Tm1; r6 = lg[NC * p + lane];
        step(r7); p = t + 15; p = p < Tm1 ? p : Tm1; r7 = lg[NC * p + lane];
    }
    // remainder <= 7 steps, rows already prefetched in r0..r6
    if (t + 0 < len) step(r0);
    if (t + 1 < len) step(r1);
    if (t + 2 < len) step(r2);
    if (t + 3 < len) step(r3);
    if (t + 4 < len) step(r4);
    if (t + 5 < len) step(r5);
    if (t + 6 < len) step(r6);

    // ---- logZ = L + log(sum_i vn_i)
    const float logZ = L + __logf(wave_sum_bcast(vn));

    // ---- gold score (parallel, off critical path)
    const int* tg = tags + (size_t)n * T;
    float g = 0.f;
    for (int tt = 1 + lane; tt < len; tt += 64) {
        const int cur = tg[tt];
        const int prv = tg[tt - 1];
        g += trans[cur * NC + prv] + lg[tt * NC + cur];
    }
    g = wave_sum_bcast(g);

    if (lane == 0) {
        const int t0 = tg[0];
        const float gold = init_alphas[t0] + lg[t0] + g;
        out[n] = logZ - gold;
    }
}

extern "C" void kernel_launch(void* const* d_in, const int* in_sizes, int n_in,
                              void* d_out, int out_size, void* d_ws, size_t ws_size,
                              hipStream_t stream)
{
    const float* logits = (const float*)d_in[0];   // [N][T][C] f32
    const float* trans  = (const float*)d_in[1];   // [C][C]    f32
    const float* inita  = (const float*)d_in[2];   // [C]       f32
    const int*   lens   = (const int*)d_in[3];     // [N]       i32
    const int*   tags   = (const int*)d_in[4];     // [N][T]    i32
    float*       out    = (float*)d_out;           // [N]       f32

    const int N = 512, T = 1024;
    crf_nll_kernel<<<N, 64, 0, stream>>>(logits, trans, inita, lens, tags, out, N, T);
}